// Round 1
// baseline (208.166 us; speedup 1.0000x reference)
//
#include <hip/hip_runtime.h>
#include <hip/hip_bf16.h>

typedef __bf16 bf16x8 __attribute__((ext_vector_type(8)));
typedef float f32x4 __attribute__((ext_vector_type(4)));

#define N 8192
#define D 512
#define NS 64   // number of spectral components (S)

// workspace layout (bytes)
#define XBF_OFF 0                          // bf16 X  [N][D]   : 8 MB
#define WT_OFF  (8 * 1024 * 1024)          // bf16 W^T [S][N]  : 1 MB
#define SQ_OFF  (WT_OFF + 1024 * 1024)     // f32 sq  [N]      : 32 KB
#define E_OFF   (SQ_OFF + 32 * 1024)       // f32 E   [S][N]   : 2 MB
#define SC_OFF  (E_OFF + N * NS * 4)       // f32 S1, S2       : 8 B

// ---------------------------------------------------------------------------
// prep_x: X fp32 -> bf16 (row-major, no pad) + row squared norms (fp32)
// one wave per row, 8 elems per lane
__global__ __launch_bounds__(256) void prep_x(const float* __restrict__ X,
                                              __bf16* __restrict__ Xbf,
                                              float* __restrict__ sq) {
    int row = blockIdx.x * 4 + (threadIdx.x >> 6);
    int lane = threadIdx.x & 63;
    const float* src = X + (size_t)row * D + lane * 8;
    float4 v0 = *(const float4*)src;
    float4 v1 = *(const float4*)(src + 4);
    bf16x8 o;
    o[0] = (__bf16)v0.x; o[1] = (__bf16)v0.y; o[2] = (__bf16)v0.z; o[3] = (__bf16)v0.w;
    o[4] = (__bf16)v1.x; o[5] = (__bf16)v1.y; o[6] = (__bf16)v1.z; o[7] = (__bf16)v1.w;
    *(bf16x8*)(Xbf + (size_t)row * D + lane * 8) = o;
    float acc = v0.x*v0.x + v0.y*v0.y + v0.z*v0.z + v0.w*v0.w
              + v1.x*v1.x + v1.y*v1.y + v1.z*v1.z + v1.w*v1.w;
    for (int off = 32; off > 0; off >>= 1) acc += __shfl_down(acc, off);
    if (lane == 0) sq[row] = acc;
}

// ---------------------------------------------------------------------------
// prep_w: W [N][S] fp32 -> W^T [S][N] bf16 via LDS tile transpose
__global__ __launch_bounds__(256) void prep_w(const float* __restrict__ W,
                                              __bf16* __restrict__ WTg) {
    __shared__ float T[64][65];
    int i0 = blockIdx.x * 64;
    int t = threadIdx.x;
    for (int j = 0; j < 16; ++j) {
        int idx = t + 256 * j;
        int r = idx >> 6;     // local i
        int c = idx & 63;     // s
        T[c][r] = W[(size_t)(i0 + r) * NS + c];   // coalesced read
    }
    __syncthreads();
    for (int j = 0; j < 16; ++j) {
        int idx = t + 256 * j;
        int s  = idx >> 6;
        int il = idx & 63;
        WTg[(size_t)s * N + i0 + il] = (__bf16)T[s][il];   // coalesced write
    }
}

// ---------------------------------------------------------------------------
// main: per block, 128 columns (n) x 1024 rows (i chunk) of K.
//  - Gram tile 128x128 via mfma_16x16x32_bf16, K over D in chunks of 32
//  - exp epilogue -> K^T tile in LDS (layout [n][i], padded to 136 for 16B align)
//  - second MFMA: E[64 s][128 n] += W^T chunk . K tile, acc persists over i-chunk
//  - atomicAdd partial E tile into global E
__global__ __launch_bounds__(256, 2) void kpca_main(
        const __bf16* __restrict__ Xbf, const __bf16* __restrict__ WTg,
        const float* __restrict__ sq, float* __restrict__ Eg) {
    // row strides: Xi/Xn 40 elems (80 B: 16B-aligned, 2-way bank alias = free)
    // KT/WT 136 elems (272 B: 16B-aligned, 2-way alias)
    __shared__ __bf16 Xi[128][40];
    __shared__ __bf16 Xn[128][40];
    __shared__ __bf16 KT[128][136];   // [n][i]
    __shared__ __bf16 WT[64][136];    // [s][i]

    const int t = threadIdx.x;
    const int w = t >> 6;
    const int l = t & 63;
    const int quad = l >> 4;
    const int l15 = l & 15;
    const int wm = w >> 1, wn = w & 1;     // 2x2 wave grid over 128x128 Gram
    const int n0 = blockIdx.x * 128;
    const int ic0 = blockIdx.y * 1024;
    const int sr = t >> 1, sh = t & 1;     // staging row / half

    float sqn_v[4];
    for (int nt = 0; nt < 4; ++nt)
        sqn_v[nt] = sq[n0 + wn * 64 + nt * 16 + l15];

    f32x4 accE[4][2];
    for (int st = 0; st < 4; ++st)
        for (int n2 = 0; n2 < 2; ++n2)
            accE[st][n2] = (f32x4){0.f, 0.f, 0.f, 0.f};

    for (int it = 0; it < 8; ++it) {
        const int i0 = ic0 + it * 128;
        f32x4 accG[4][4];
        for (int mt = 0; mt < 4; ++mt)
            for (int nt = 0; nt < 4; ++nt)
                accG[mt][nt] = (f32x4){0.f, 0.f, 0.f, 0.f};

        for (int kc = 0; kc < D; kc += 32) {
            __syncthreads();   // protect LDS (also orders prev 2nd-mfma reads)
            const __bf16* g1 = Xbf + (size_t)(i0 + sr) * D + kc + sh * 16;
            *(bf16x8*)&Xi[sr][sh * 16]     = *(const bf16x8*)g1;
            *(bf16x8*)&Xi[sr][sh * 16 + 8] = *(const bf16x8*)(g1 + 8);
            const __bf16* g2 = Xbf + (size_t)(n0 + sr) * D + kc + sh * 16;
            *(bf16x8*)&Xn[sr][sh * 16]     = *(const bf16x8*)g2;
            *(bf16x8*)&Xn[sr][sh * 16 + 8] = *(const bf16x8*)(g2 + 8);
            __syncthreads();
            bf16x8 a[4], b[4];
            for (int mt = 0; mt < 4; ++mt)
                a[mt] = *(const bf16x8*)&Xi[wm * 64 + mt * 16 + l15][quad * 8];
            for (int nt = 0; nt < 4; ++nt)
                b[nt] = *(const bf16x8*)&Xn[wn * 64 + nt * 16 + l15][quad * 8];
            for (int mt = 0; mt < 4; ++mt)
                for (int nt = 0; nt < 4; ++nt)
                    accG[mt][nt] = __builtin_amdgcn_mfma_f32_16x16x32_bf16(
                        a[mt], b[nt], accG[mt][nt], 0, 0, 0);
        }

        // epilogue: d2 -> exp -> bf16 -> KT[n][i]  (C layout: col(n)=l15, row(i)=quad*4+r)
        for (int mt = 0; mt < 4; ++mt) {
            int ibase = wm * 64 + mt * 16 + quad * 4;
            float si[4];
            for (int r = 0; r < 4; ++r) si[r] = sq[i0 + ibase + r];
            for (int nt = 0; nt < 4; ++nt) {
                int nloc = wn * 64 + nt * 16 + l15;
                float sn = sqn_v[nt];
                union { __bf16 h[4]; uint2 u; } pk;
                for (int r = 0; r < 4; ++r) {
                    float d2 = si[r] + sn - 2.0f * accG[mt][nt][r];
                    pk.h[r] = (__bf16)__expf(d2 * -0.0009765625f);  // exp(-d2/1024)
                }
                *(uint2*)&KT[nloc][ibase] = pk.u;   // 8B aligned store
            }
        }
        // stage W^T chunk [64 s][128 i]
        for (int j = 0; j < 4; ++j) {
            int g = t + 256 * j;
            int s = g >> 4;
            int seg = g & 15;
            *(bf16x8*)&WT[s][seg * 8] =
                *(const bf16x8*)(WTg + (size_t)s * N + i0 + seg * 8);
        }
        __syncthreads();

        // E[s][n] += sum_i WT[s][i] * KT[n][i] ; wave w owns n in [w*32, w*32+32)
        for (int kc2 = 0; kc2 < 4; ++kc2) {
            bf16x8 aw[4], bk[2];
            for (int st = 0; st < 4; ++st)
                aw[st] = *(const bf16x8*)&WT[st * 16 + l15][kc2 * 32 + quad * 8];
            for (int n2 = 0; n2 < 2; ++n2)
                bk[n2] = *(const bf16x8*)&KT[w * 32 + n2 * 16 + l15][kc2 * 32 + quad * 8];
            for (int st = 0; st < 4; ++st)
                for (int n2 = 0; n2 < 2; ++n2)
                    accE[st][n2] = __builtin_amdgcn_mfma_f32_16x16x32_bf16(
                        aw[st], bk[n2], accE[st][n2], 0, 0, 0);
        }
    }

    for (int st = 0; st < 4; ++st)
        for (int n2 = 0; n2 < 2; ++n2)
            for (int r = 0; r < 4; ++r) {
                int s = st * 16 + quad * 4 + r;
                int n = n0 + w * 32 + n2 * 16 + l15;
                atomicAdd(Eg + (size_t)s * N + n, accE[st][n2][r]);
            }
}

// ---------------------------------------------------------------------------
// loss: one block per s: S1 += lam[s]*sum_n E^2 ; S2 += sum_n E*W[n][s]
__global__ __launch_bounds__(256) void loss_kernel(const float* __restrict__ Eg,
                                                   const float* __restrict__ W,
                                                   const float* __restrict__ lam,
                                                   float* __restrict__ Sacc) {
    int s = blockIdx.x;
    int t = threadIdx.x;
    float a1 = 0.f, a2 = 0.f;
    for (int n = t; n < N; n += 256) {
        float e = Eg[(size_t)s * N + n];
        a1 += e * e;
        a2 += e * W[(size_t)n * NS + s];
    }
    for (int off = 32; off > 0; off >>= 1) {
        a1 += __shfl_down(a1, off);
        a2 += __shfl_down(a2, off);
    }
    __shared__ float r1[4], r2[4];
    int wv = t >> 6, ln = t & 63;
    if (ln == 0) { r1[wv] = a1; r2[wv] = a2; }
    __syncthreads();
    if (t == 0) {
        float s1 = r1[0] + r1[1] + r1[2] + r1[3];
        float s2 = r2[0] + r2[1] + r2[2] + r2[3];
        atomicAdd(Sacc + 0, lam[s] * s1);
        atomicAdd(Sacc + 1, s2);
    }
}

__global__ void finalize(const float* __restrict__ Sacc, float* __restrict__ out) {
    float L = 0.5f * (Sacc[1] - Sacc[0]);   // loss1=-S1/2, loss2=S2/2 (eta=1)
    out[0] = L + 0.05f * L * L;             // C_STAB/2 = 0.05
}

// ---------------------------------------------------------------------------
extern "C" void kernel_launch(void* const* d_in, const int* in_sizes, int n_in,
                              void* d_out, int out_size, void* d_ws, size_t ws_size,
                              hipStream_t stream) {
    const float* X   = (const float*)d_in[0];   // [8192][512]
    const float* W   = (const float*)d_in[1];   // [8192][64]
    const float* lam = (const float*)d_in[2];   // [64]
    float* out = (float*)d_out;
    char* ws = (char*)d_ws;
    __bf16* Xbf = (__bf16*)(ws + XBF_OFF);
    __bf16* WTg = (__bf16*)(ws + WT_OFF);
    float* sq   = (float*)(ws + SQ_OFF);
    float* Eg   = (float*)(ws + E_OFF);
    float* Sacc = (float*)(ws + SC_OFF);

    hipMemsetAsync(Eg, 0, (size_t)N * NS * 4 + 8, stream);   // E + S1/S2
    prep_x<<<N / 4, 256, 0, stream>>>(X, Xbf, sq);
    prep_w<<<N / 64, 256, 0, stream>>>(W, WTg);
    kpca_main<<<dim3(64, 8), 256, 0, stream>>>(Xbf, WTg, sq, Eg);
    loss_kernel<<<NS, 256, 0, stream>>>(Eg, W, lam, Sacc);
    finalize<<<1, 1, 0, stream>>>(Sacc, out);
}